// Round 8
// baseline (2440.426 us; speedup 1.0000x reference)
//
#include <hip/hip_runtime.h>

#define TT   2048
#define BB   512
#define IN_  27
#define HH   64
#define NG   256   // 4*H
#define OUTD 26
#define EPSV 1e-5f

__device__ __forceinline__ float bcastf(float v, int lane) {
    return __int_as_float(__builtin_amdgcn_readlane(__float_as_int(v), lane));
}

__device__ __forceinline__ float sigm(float x) {
    return 1.0f / (1.0f + __expf(-x));
}

__device__ __forceinline__ float tanh_fast(float x) {
    float e = __expf(-2.0f * fabsf(x));
    float r = (1.0f - e) / (1.0f + e);
    return copysignf(r, x);
}

// Phase 0: pre-gates GEMM (fully parallel, no recurrence):
// pre_g[tl][b][j] = b_ih[j] + b_hh[j] + sum_k W_ih[j,k] * x[t0+tl][b][k].
// One block per (t, 8 batch elements); thread = gate row j.
__global__ __launch_bounds__(256, 2) void pregemm(
    const float* __restrict__ x,     // [T,B,IN]
    const float* __restrict__ W_ih,  // [NG,IN]
    const float* __restrict__ b_ih,  // [NG]
    const float* __restrict__ b_hh,  // [NG]
    float* __restrict__ pre_g,       // [tc,B,NG] (workspace)
    int t0, int tc)
{
    const int tl = blockIdx.x;
    const int b0 = blockIdx.y * 8;
    const int j  = threadIdx.x;

    __shared__ float s_x[8][IN_];
    if (j < 8 * IN_) {
        const int bi = j / IN_, k = j % IN_;
        s_x[bi][k] = x[(((size_t)(t0 + tl)) * BB + b0 + bi) * IN_ + k];
    }

    const float bias = b_ih[j] + b_hh[j];
    float w[IN_];
#pragma unroll
    for (int k = 0; k < IN_; ++k) w[k] = W_ih[j * IN_ + k];
    __syncthreads();

#pragma unroll
    for (int bi = 0; bi < 8; ++bi) {
        float acc = bias;
#pragma unroll
        for (int k = 0; k < IN_; ++k) acc = fmaf(w[k], s_x[bi][k], acc);
        pre_g[((size_t)tl * BB + b0 + bi) * NG + j] = acc;  // coalesced
    }
}

// Phase 1: sequential LSTM. FOUR waves per batch element, ONE gate per wave.
//
// ROUND-7 LESSON: waves_per_eu(2,2) bound (VGPR 56->88) but demand (~150:
// 64 wh + 27 wi + working) still exceeded the grant -> ~60 weights spilled
// to scratch, reloaded every step, dur unchanged. r0 (demand 27: kept) and
// r7 (granted 88) bracket the allocator: we can't raise the grant, but we
// can FIT UNDER it. The x-dot has no recurrence -> hoisted to pregemm.
// Serial-loop demand is now 64 W_hh + ~16 working ~= 80 <= 88: zero-spill
// is the allocator's cheapest option. Per step: 1 prefetched pre_g load +
// 64 readlane + 64 FMA + act + 1 LDS wr + 1 barrier + 4 LDS rd + cell.
__global__ void __launch_bounds__(256)
__attribute__((amdgpu_waves_per_eu(2, 2)))
lstm_seq(
    const float* __restrict__ pre_g, // [tc,B,NG] (from pregemm)
    const float* __restrict__ W_hh,  // [NG,H]
    float* __restrict__ h_all,       // [tc,B,H] (workspace)
    float* __restrict__ state,       // [2,B,H]  (workspace: h then c)
    int tc, int first)
{
    const int b   = blockIdx.x;
    const int wid = threadIdx.x >> 6;   // gate: 0=i 1=f 2=g 3=o
    const int l   = threadIdx.x & 63;   // h index
    const int j   = wid * HH + l;       // gate row

    // ---- W_hh row j: 64 named scalars (merged to dwordx4 loads) ----
    const float* Wp = W_hh + j * HH;
    float wh0 =Wp[0],  wh1 =Wp[1],  wh2 =Wp[2],  wh3 =Wp[3];
    float wh4 =Wp[4],  wh5 =Wp[5],  wh6 =Wp[6],  wh7 =Wp[7];
    float wh8 =Wp[8],  wh9 =Wp[9],  wh10=Wp[10], wh11=Wp[11];
    float wh12=Wp[12], wh13=Wp[13], wh14=Wp[14], wh15=Wp[15];
    float wh16=Wp[16], wh17=Wp[17], wh18=Wp[18], wh19=Wp[19];
    float wh20=Wp[20], wh21=Wp[21], wh22=Wp[22], wh23=Wp[23];
    float wh24=Wp[24], wh25=Wp[25], wh26=Wp[26], wh27=Wp[27];
    float wh28=Wp[28], wh29=Wp[29], wh30=Wp[30], wh31=Wp[31];
    float wh32=Wp[32], wh33=Wp[33], wh34=Wp[34], wh35=Wp[35];
    float wh36=Wp[36], wh37=Wp[37], wh38=Wp[38], wh39=Wp[39];
    float wh40=Wp[40], wh41=Wp[41], wh42=Wp[42], wh43=Wp[43];
    float wh44=Wp[44], wh45=Wp[45], wh46=Wp[46], wh47=Wp[47];
    float wh48=Wp[48], wh49=Wp[49], wh50=Wp[50], wh51=Wp[51];
    float wh52=Wp[52], wh53=Wp[53], wh54=Wp[54], wh55=Wp[55];
    float wh56=Wp[56], wh57=Wp[57], wh58=Wp[58], wh59=Wp[59];
    float wh60=Wp[60], wh61=Wp[61], wh62=Wp[62], wh63=Wp[63];

    // ---- scalar launder: defs opaque; remat-from-memory impossible ----
    asm volatile("" : "+v"(wh0), "+v"(wh1), "+v"(wh2), "+v"(wh3),
                      "+v"(wh4), "+v"(wh5), "+v"(wh6), "+v"(wh7),
                      "+v"(wh8), "+v"(wh9), "+v"(wh10), "+v"(wh11),
                      "+v"(wh12), "+v"(wh13), "+v"(wh14), "+v"(wh15));
    asm volatile("" : "+v"(wh16), "+v"(wh17), "+v"(wh18), "+v"(wh19),
                      "+v"(wh20), "+v"(wh21), "+v"(wh22), "+v"(wh23),
                      "+v"(wh24), "+v"(wh25), "+v"(wh26), "+v"(wh27),
                      "+v"(wh28), "+v"(wh29), "+v"(wh30), "+v"(wh31));
    asm volatile("" : "+v"(wh32), "+v"(wh33), "+v"(wh34), "+v"(wh35),
                      "+v"(wh36), "+v"(wh37), "+v"(wh38), "+v"(wh39),
                      "+v"(wh40), "+v"(wh41), "+v"(wh42), "+v"(wh43),
                      "+v"(wh44), "+v"(wh45), "+v"(wh46), "+v"(wh47));
    asm volatile("" : "+v"(wh48), "+v"(wh49), "+v"(wh50), "+v"(wh51),
                      "+v"(wh52), "+v"(wh53), "+v"(wh54), "+v"(wh55),
                      "+v"(wh56), "+v"(wh57), "+v"(wh58), "+v"(wh59),
                      "+v"(wh60), "+v"(wh61), "+v"(wh62), "+v"(wh63));

    float hv, cv;
    if (first) {
        hv = 0.0f; cv = 0.0f;
    } else {
        hv = state[b * HH + l];
        cv = state[BB * HH + b * HH + l];
    }

    // acts[dbuf][gate][lane]; double-buffered -> exactly 1 barrier/step
    __shared__ float acts[2][4][HH];

#define HD(k, acc) acc = fmaf(bcastf(hv, k), wh##k, acc);

    const float* pgp = pre_g + (size_t)b * NG + j;
    // prefetch pre-gate for tl=0
    float pgv = pgp[0];

    float* hout = h_all + (size_t)b * HH + l;

#pragma unroll 1
    for (int tl = 0; tl < tc; ++tl) {
        // consume prefetched pre-gate, then immediately issue the next load
        // so its L3/L2 latency hides under the 128-instr h-dot below.
        float a0 = pgv, a1 = 0.0f, a2 = 0.0f, a3 = 0.0f;
        int tn = tl + 1; if (tn > tc - 1) tn = tc - 1;   // clamp (stay in ws)
        pgv = pgp[(size_t)tn * BB * NG];

        HD(0,a0)  HD(1,a1)  HD(2,a2)  HD(3,a3)
        HD(4,a0)  HD(5,a1)  HD(6,a2)  HD(7,a3)
        HD(8,a0)  HD(9,a1)  HD(10,a2) HD(11,a3)
        HD(12,a0) HD(13,a1) HD(14,a2) HD(15,a3)
        HD(16,a0) HD(17,a1) HD(18,a2) HD(19,a3)
        HD(20,a0) HD(21,a1) HD(22,a2) HD(23,a3)
        HD(24,a0) HD(25,a1) HD(26,a2) HD(27,a3)
        HD(28,a0) HD(29,a1) HD(30,a2) HD(31,a3)
        HD(32,a0) HD(33,a1) HD(34,a2) HD(35,a3)
        HD(36,a0) HD(37,a1) HD(38,a2) HD(39,a3)
        HD(40,a0) HD(41,a1) HD(42,a2) HD(43,a3)
        HD(44,a0) HD(45,a1) HD(46,a2) HD(47,a3)
        HD(48,a0) HD(49,a1) HD(50,a2) HD(51,a3)
        HD(52,a0) HD(53,a1) HD(54,a2) HD(55,a3)
        HD(56,a0) HD(57,a1) HD(58,a2) HD(59,a3)
        HD(60,a0) HD(61,a1) HD(62,a2) HD(63,a3)
        const float acc = (a0 + a1) + (a2 + a3);

        // own gate's activation (branch is wave-uniform: wid==2 is g)
        const float av = (wid == 2) ? tanh_fast(acc) : sigm(acc);

        acts[tl & 1][wid][l] = av;
        __syncthreads();

        // cell update (redundant across the 4 waves; lane-local)
        const float gi = acts[tl & 1][0][l];
        const float gf = acts[tl & 1][1][l];
        const float gg = acts[tl & 1][2][l];
        const float go = acts[tl & 1][3][l];
        cv = fmaf(gf, cv, gi * gg);
        hv = go * tanh_fast(cv);

        if (wid == 0) {
            *hout = hv;                    // coalesced 256B store per wave
            hout += (size_t)BB * HH;
        }
        // no second barrier: next step writes the OTHER acts buffer; this
        // one is re-written only after the NEXT barrier (all waves' reads of
        // it precede that barrier in program order).
    }

#undef HD

    if (wid == 0) {
        state[b * HH + l] = hv;
        state[BB * HH + b * HH + l] = cv;
    }
}

// Phase 2: per-timestep BatchNorm (batch stats) + locked dropout + maxpool
// over batch + FC. One block per timestep, fully parallel over tc.
// Unchanged from the verified round-0 kernel.
__global__ __launch_bounds__(256, 2) void bn_pool_fc(
    const float* __restrict__ h_all,  // [tc,B,H]
    const float* __restrict__ gamma,  // [H]
    const float* __restrict__ beta,   // [H]
    const float* __restrict__ dmask,  // [B,H]
    const float* __restrict__ pg,     // [T,OUT]
    const float* __restrict__ W_fc,   // [OUT, H+OUT]
    const float* __restrict__ b_fc,   // [OUT]
    float* __restrict__ y,            // [T,OUT]
    int t0, int tc)
{
    const int tl = blockIdx.x;
    const int t = t0 + tl;
    const int tid = threadIdx.x;
    const int g = tid >> 6;      // 4 batch groups
    const int hcol = tid & 63;
    const float* hp = h_all + (size_t)tl * BB * HH;

    __shared__ float s_a[4][HH];
    __shared__ float s_b[4][HH];
    __shared__ float s_scale[HH];
    __shared__ float s_shift[HH];
    __shared__ float s_pool[HH];

    // pass 1: sum and sumsq over batch (coalesced: lane = hcol)
    float sum = 0.0f, sq = 0.0f;
    for (int bb = g; bb < BB; bb += 4) {
        const float v = hp[bb * HH + hcol];
        sum += v;
        sq = fmaf(v, v, sq);
    }
    s_a[g][hcol] = sum;
    s_b[g][hcol] = sq;
    __syncthreads();

    if (tid < HH) {
        const float s  = (s_a[0][tid] + s_a[1][tid]) + (s_a[2][tid] + s_a[3][tid]);
        const float q2 = (s_b[0][tid] + s_b[1][tid]) + (s_b[2][tid] + s_b[3][tid]);
        const float mean = s * (1.0f / BB);
        const float var  = q2 * (1.0f / BB) - mean * mean;  // biased var
        const float rs = rsqrtf(var + EPSV);
        const float sc = rs * gamma[tid];
        s_scale[tid] = sc;
        s_shift[tid] = beta[tid] - mean * sc;
    }
    __syncthreads();

    // pass 2: normalize + locked dropout + max over batch
    const float sc = s_scale[hcol];
    const float sh = s_shift[hcol];
    float m = -3.0e38f;
    for (int bb = g; bb < BB; bb += 4) {
        const float v = hp[bb * HH + hcol];
        const float hd = fmaf(v, sc, sh) * dmask[bb * HH + hcol];
        m = fmaxf(m, hd);
    }
    s_a[g][hcol] = m;
    __syncthreads();
    if (tid < HH) {
        s_pool[tid] = fmaxf(fmaxf(s_a[0][tid], s_a[1][tid]),
                            fmaxf(s_a[2][tid], s_a[3][tid]));
    }
    __syncthreads();

    // FC: y[t, o] = b_fc[o] + W_fc[o, 0:64].pool + W_fc[o, 64:90].pg[t]
    if (tid < OUTD) {
        float acc = b_fc[tid];
        const float* w = W_fc + tid * (HH + OUTD);
#pragma unroll
        for (int k = 0; k < HH; ++k) acc = fmaf(w[k], s_pool[k], acc);
#pragma unroll
        for (int k = 0; k < OUTD; ++k) acc = fmaf(w[HH + k], pg[t * OUTD + k], acc);
        y[t * OUTD + tid] = acc;
    }
}

extern "C" void kernel_launch(void* const* d_in, const int* in_sizes, int n_in,
                              void* d_out, int out_size, void* d_ws, size_t ws_size,
                              hipStream_t stream)
{
    const float* x     = (const float*)d_in[0];   // [T,B,IN]
    const float* pg    = (const float*)d_in[1];   // [T,OUT]
    const float* W_ih  = (const float*)d_in[2];   // [4H,IN]
    const float* W_hh  = (const float*)d_in[3];   // [4H,H]
    const float* b_ih  = (const float*)d_in[4];
    const float* b_hh  = (const float*)d_in[5];
    const float* gamma = (const float*)d_in[6];
    const float* beta  = (const float*)d_in[7];
    const float* W_fc  = (const float*)d_in[8];   // [OUT,H+OUT]
    const float* b_fc  = (const float*)d_in[9];
    const float* dmask = (const float*)d_in[10];  // [B,H]
    float* y = (float*)d_out;

    // Workspace: h_all[chunkT,B,H] + pre_g[chunkT,B,NG] + state[2,B,H].
    const size_t state_bytes = 2ull * BB * HH * sizeof(float);
    const size_t per_t = (size_t)BB * (HH + NG) * sizeof(float);
    size_t avail = (ws_size > state_bytes) ? (ws_size - state_bytes) : 0;
    int chunkT = (int)(avail / per_t);
    if (chunkT > TT) chunkT = TT;
    if (chunkT < 1) chunkT = 1;

    float* h_all = (float*)d_ws;
    float* preg  = h_all + (size_t)chunkT * BB * HH;
    float* state = preg  + (size_t)chunkT * BB * NG;

    int first = 1;
    for (int t0 = 0; t0 < TT; t0 += chunkT) {
        int tc = TT - t0;
        if (tc > chunkT) tc = chunkT;
        pregemm<<<dim3(tc, BB / 8), 256, 0, stream>>>(x, W_ih, b_ih, b_hh,
                                                      preg, t0, tc);
        lstm_seq<<<BB, 256, 0, stream>>>(preg, W_hh, h_all, state, tc, first);
        bn_pool_fc<<<tc, 256, 0, stream>>>(h_all, gamma, beta, dmask, pg,
                                           W_fc, b_fc, y, t0, tc);
        first = 0;
    }
}

// Round 9
// 2398.837 us; speedup vs baseline: 1.0173x; 1.0173x over previous
//
#include <hip/hip_runtime.h>

#define TT   2048
#define BB   512
#define IN_  27
#define HH   64
#define NG   256   // 4*H
#define OUTD 26
#define EPSV 1e-5f

__device__ __forceinline__ float bcastf(float v, int lane) {
    return __int_as_float(__builtin_amdgcn_readlane(__float_as_int(v), lane));
}

__device__ __forceinline__ float sigm(float x) {
    return 1.0f / (1.0f + __expf(-x));
}

__device__ __forceinline__ float tanh_fast(float x) {
    float e = __expf(-2.0f * fabsf(x));
    float r = (1.0f - e) / (1.0f + e);
    return copysignf(r, x);
}

// Phase 0: pre-gates GEMM (fully parallel, no recurrence). Unchanged from r8.
__global__ __launch_bounds__(256, 2) void pregemm(
    const float* __restrict__ x,     // [T,B,IN]
    const float* __restrict__ W_ih,  // [NG,IN]
    const float* __restrict__ b_ih,  // [NG]
    const float* __restrict__ b_hh,  // [NG]
    float* __restrict__ pre_g,       // [tc,B,NG] (workspace)
    int t0, int tc)
{
    const int tl = blockIdx.x;
    const int b0 = blockIdx.y * 8;
    const int j  = threadIdx.x;

    __shared__ float s_x[8][IN_];
    if (j < 8 * IN_) {
        const int bi = j / IN_, k = j % IN_;
        s_x[bi][k] = x[(((size_t)(t0 + tl)) * BB + b0 + bi) * IN_ + k];
    }

    const float bias = b_ih[j] + b_hh[j];
    float w[IN_];
#pragma unroll
    for (int k = 0; k < IN_; ++k) w[k] = W_ih[j * IN_ + k];
    __syncthreads();

#pragma unroll
    for (int bi = 0; bi < 8; ++bi) {
        float acc = bias;
#pragma unroll
        for (int k = 0; k < IN_; ++k) acc = fmaf(w[k], s_x[bi][k], acc);
        pre_g[((size_t)tl * BB + b0 + bi) * NG + j] = acc;  // coalesced
    }
}

// Phase 1: sequential LSTM. FOUR waves per batch element, ONE gate per wave.
// W_hh register-resident (r8: VGPR=88, verified by the 2185->595us/683-step
// drop).
//
// ROUND-8 LESSON: remaining stall is the __syncthreads barrier DRAIN —
// compiler emits `s_waitcnt vmcnt(0)` before s_barrier, so the 1-deep pre_g
// prefetch is waited to completion EVERY step (~600cy of exposed HBM/L3
// latency on top of ~680cy issue). Fix (T4, counted-not-drained):
//   (a) raw `s_waitcnt lgkmcnt(0); s_barrier` — LDS publish needs only
//       lgkm; global loads stay in flight across the barrier;
//   (b) prefetch depth 2 via 2x-unrolled loop with TWO phase registers
//       (no rotation movs — a mov would force the vmcnt wait 1 step early).
// Safety of relaxed barrier: acts[] is double-buffered; each wave's reads
// of buf[t&1] precede its own lgkmcnt(0)+barrier at t+1, and buf[t&1] is
// only overwritten after barrier t+1 -> no race without any vmcnt drain.
__global__ void __launch_bounds__(256)
__attribute__((amdgpu_waves_per_eu(2, 2)))
lstm_seq(
    const float* __restrict__ pre_g, // [tc,B,NG] (from pregemm)
    const float* __restrict__ W_hh,  // [NG,H]
    float* __restrict__ h_all,       // [tc,B,H] (workspace)
    float* __restrict__ state,       // [2,B,H]  (workspace: h then c)
    int tc, int first)
{
    const int b   = blockIdx.x;
    const int wid = threadIdx.x >> 6;   // gate: 0=i 1=f 2=g 3=o
    const int l   = threadIdx.x & 63;   // h index
    const int j   = wid * HH + l;       // gate row

    // ---- W_hh row j: 64 named scalars (merged to dwordx4 loads) ----
    const float* Wp = W_hh + j * HH;
    float wh0 =Wp[0],  wh1 =Wp[1],  wh2 =Wp[2],  wh3 =Wp[3];
    float wh4 =Wp[4],  wh5 =Wp[5],  wh6 =Wp[6],  wh7 =Wp[7];
    float wh8 =Wp[8],  wh9 =Wp[9],  wh10=Wp[10], wh11=Wp[11];
    float wh12=Wp[12], wh13=Wp[13], wh14=Wp[14], wh15=Wp[15];
    float wh16=Wp[16], wh17=Wp[17], wh18=Wp[18], wh19=Wp[19];
    float wh20=Wp[20], wh21=Wp[21], wh22=Wp[22], wh23=Wp[23];
    float wh24=Wp[24], wh25=Wp[25], wh26=Wp[26], wh27=Wp[27];
    float wh28=Wp[28], wh29=Wp[29], wh30=Wp[30], wh31=Wp[31];
    float wh32=Wp[32], wh33=Wp[33], wh34=Wp[34], wh35=Wp[35];
    float wh36=Wp[36], wh37=Wp[37], wh38=Wp[38], wh39=Wp[39];
    float wh40=Wp[40], wh41=Wp[41], wh42=Wp[42], wh43=Wp[43];
    float wh44=Wp[44], wh45=Wp[45], wh46=Wp[46], wh47=Wp[47];
    float wh48=Wp[48], wh49=Wp[49], wh50=Wp[50], wh51=Wp[51];
    float wh52=Wp[52], wh53=Wp[53], wh54=Wp[54], wh55=Wp[55];
    float wh56=Wp[56], wh57=Wp[57], wh58=Wp[58], wh59=Wp[59];
    float wh60=Wp[60], wh61=Wp[61], wh62=Wp[62], wh63=Wp[63];

    // ---- scalar launder: defs opaque; remat-from-memory impossible ----
    asm volatile("" : "+v"(wh0), "+v"(wh1), "+v"(wh2), "+v"(wh3),
                      "+v"(wh4), "+v"(wh5), "+v"(wh6), "+v"(wh7),
                      "+v"(wh8), "+v"(wh9), "+v"(wh10), "+v"(wh11),
                      "+v"(wh12), "+v"(wh13), "+v"(wh14), "+v"(wh15));
    asm volatile("" : "+v"(wh16), "+v"(wh17), "+v"(wh18), "+v"(wh19),
                      "+v"(wh20), "+v"(wh21), "+v"(wh22), "+v"(wh23),
                      "+v"(wh24), "+v"(wh25), "+v"(wh26), "+v"(wh27),
                      "+v"(wh28), "+v"(wh29), "+v"(wh30), "+v"(wh31));
    asm volatile("" : "+v"(wh32), "+v"(wh33), "+v"(wh34), "+v"(wh35),
                      "+v"(wh36), "+v"(wh37), "+v"(wh38), "+v"(wh39),
                      "+v"(wh40), "+v"(wh41), "+v"(wh42), "+v"(wh43),
                      "+v"(wh44), "+v"(wh45), "+v"(wh46), "+v"(wh47));
    asm volatile("" : "+v"(wh48), "+v"(wh49), "+v"(wh50), "+v"(wh51),
                      "+v"(wh52), "+v"(wh53), "+v"(wh54), "+v"(wh55),
                      "+v"(wh56), "+v"(wh57), "+v"(wh58), "+v"(wh59),
                      "+v"(wh60), "+v"(wh61), "+v"(wh62), "+v"(wh63));

    float hv, cv;
    if (first) {
        hv = 0.0f; cv = 0.0f;
    } else {
        hv = state[b * HH + l];
        cv = state[BB * HH + b * HH + l];
    }

    // acts[dbuf][gate][lane]; double-buffered -> exactly 1 barrier/step
    __shared__ float acts[2][4][HH];

#define HD(k, acc) acc = fmaf(bcastf(hv, k), wh##k, acc);

    const size_t stride = (size_t)BB * NG;          // elements per timestep
    const float* pgp  = pre_g + (size_t)b * NG + j;
    const float* pend = pgp + (size_t)(tc - 1) * stride;  // clamp target

    // Prologue: fill both phase registers (clamped for tiny tc).
    float pgvA = pgp[0];
    float pgvB = pgp[(tc > 1 ? stride : 0)];
    const float* pf = pgp + 2 * stride;             // next prefetch: step 2

    float* hout = h_all + (size_t)b * HH + l;

    // One LSTM step. BUF is the compile-time acts buffer index; PGV the
    // phase register consumed this step and refilled for step t+2.
#define LSTEP(BUF, PGV)                                                     \
    {                                                                       \
        float a0 = PGV, a1 = 0.0f, a2 = 0.0f, a3 = 0.0f;                    \
        /* depth-2 prefetch: refill PGV for t+2 (clamped); consumed 2  */   \
        /* steps from now -> ~2 full steps of latency cover.           */   \
        {                                                                   \
            const float* pfc = (pf < pend) ? pf : pend;                     \
            PGV = *pfc;                                                     \
            pf += stride;                                                   \
        }                                                                   \
        HD(0,a0)  HD(1,a1)  HD(2,a2)  HD(3,a3)                              \
        HD(4,a0)  HD(5,a1)  HD(6,a2)  HD(7,a3)                              \
        HD(8,a0)  HD(9,a1)  HD(10,a2) HD(11,a3)                             \
        HD(12,a0) HD(13,a1) HD(14,a2) HD(15,a3)                             \
        HD(16,a0) HD(17,a1) HD(18,a2) HD(19,a3)                             \
        HD(20,a0) HD(21,a1) HD(22,a2) HD(23,a3)                             \
        HD(24,a0) HD(25,a1) HD(26,a2) HD(27,a3)                             \
        HD(28,a0) HD(29,a1) HD(30,a2) HD(31,a3)                             \
        HD(32,a0) HD(33,a1) HD(34,a2) HD(35,a3)                             \
        HD(36,a0) HD(37,a1) HD(38,a2) HD(39,a3)                             \
        HD(40,a0) HD(41,a1) HD(42,a2) HD(43,a3)                             \
        HD(44,a0) HD(45,a1) HD(46,a2) HD(47,a3)                             \
        HD(48,a0) HD(49,a1) HD(50,a2) HD(51,a3)                             \
        HD(52,a0) HD(53,a1) HD(54,a2) HD(55,a3)                             \
        HD(56,a0) HD(57,a1) HD(58,a2) HD(59,a3)                             \
        HD(60,a0) HD(61,a1) HD(62,a2) HD(63,a3)                             \
        const float acc = (a0 + a1) + (a2 + a3);                            \
        const float av = (wid == 2) ? tanh_fast(acc) : sigm(acc);           \
        acts[BUF][wid][l] = av;                                             \
        /* publish LDS only (lgkm); do NOT drain vmcnt: prefetches stay */  \
        /* in flight across the barrier (T4).                           */  \
        asm volatile("s_waitcnt lgkmcnt(0)" ::: "memory");                  \
        __builtin_amdgcn_s_barrier();                                       \
        asm volatile("" ::: "memory");                                      \
        const float gi = acts[BUF][0][l];                                   \
        const float gf = acts[BUF][1][l];                                   \
        const float gg = acts[BUF][2][l];                                   \
        const float go = acts[BUF][3][l];                                   \
        cv = fmaf(gf, cv, gi * gg);                                         \
        hv = go * tanh_fast(cv);                                            \
        if (wid == 0) {                                                     \
            *hout = hv;                                                     \
            hout += (size_t)BB * HH;                                        \
        }                                                                   \
    }

    int tl = 0;
#pragma unroll 1
    for (; tl + 1 < tc; tl += 2) {
        LSTEP(0, pgvA)     // even step
        LSTEP(1, pgvB)     // odd step
    }
    if (tl < tc) {
        LSTEP(0, pgvA)     // tc odd: one final step
    }

#undef LSTEP
#undef HD

    if (wid == 0) {
        state[b * HH + l] = hv;
        state[BB * HH + b * HH + l] = cv;
    }
}

// Phase 2: per-timestep BatchNorm (batch stats) + locked dropout + maxpool
// over batch + FC. One block per timestep, fully parallel over tc.
// Unchanged from the verified round-0 kernel.
__global__ __launch_bounds__(256, 2) void bn_pool_fc(
    const float* __restrict__ h_all,  // [tc,B,H]
    const float* __restrict__ gamma,  // [H]
    const float* __restrict__ beta,   // [H]
    const float* __restrict__ dmask,  // [B,H]
    const float* __restrict__ pg,     // [T,OUT]
    const float* __restrict__ W_fc,   // [OUT, H+OUT]
    const float* __restrict__ b_fc,   // [OUT]
    float* __restrict__ y,            // [T,OUT]
    int t0, int tc)
{
    const int tl = blockIdx.x;
    const int t = t0 + tl;
    const int tid = threadIdx.x;
    const int g = tid >> 6;      // 4 batch groups
    const int hcol = tid & 63;
    const float* hp = h_all + (size_t)tl * BB * HH;

    __shared__ float s_a[4][HH];
    __shared__ float s_b[4][HH];
    __shared__ float s_scale[HH];
    __shared__ float s_shift[HH];
    __shared__ float s_pool[HH];

    // pass 1: sum and sumsq over batch (coalesced: lane = hcol)
    float sum = 0.0f, sq = 0.0f;
    for (int bb = g; bb < BB; bb += 4) {
        const float v = hp[bb * HH + hcol];
        sum += v;
        sq = fmaf(v, v, sq);
    }
    s_a[g][hcol] = sum;
    s_b[g][hcol] = sq;
    __syncthreads();

    if (tid < HH) {
        const float s  = (s_a[0][tid] + s_a[1][tid]) + (s_a[2][tid] + s_a[3][tid]);
        const float q2 = (s_b[0][tid] + s_b[1][tid]) + (s_b[2][tid] + s_b[3][tid]);
        const float mean = s * (1.0f / BB);
        const float var  = q2 * (1.0f / BB) - mean * mean;  // biased var
        const float rs = rsqrtf(var + EPSV);
        const float sc = rs * gamma[tid];
        s_scale[tid] = sc;
        s_shift[tid] = beta[tid] - mean * sc;
    }
    __syncthreads();

    // pass 2: normalize + locked dropout + max over batch
    const float sc = s_scale[hcol];
    const float sh = s_shift[hcol];
    float m = -3.0e38f;
    for (int bb = g; bb < BB; bb += 4) {
        const float v = hp[bb * HH + hcol];
        const float hd = fmaf(v, sc, sh) * dmask[bb * HH + hcol];
        m = fmaxf(m, hd);
    }
    s_a[g][hcol] = m;
    __syncthreads();
    if (tid < HH) {
        s_pool[tid] = fmaxf(fmaxf(s_a[0][tid], s_a[1][tid]),
                            fmaxf(s_a[2][tid], s_a[3][tid]));
    }
    __syncthreads();

    // FC: y[t, o] = b_fc[o] + W_fc[o, 0:64].pool + W_fc[o, 64:90].pg[t]
    if (tid < OUTD) {
        float acc = b_fc[tid];
        const float* w = W_fc + tid * (HH + OUTD);
#pragma unroll
        for (int k = 0; k < HH; ++k) acc = fmaf(w[k], s_pool[k], acc);
#pragma unroll
        for (int k = 0; k < OUTD; ++k) acc = fmaf(w[HH + k], pg[t * OUTD + k], acc);
        y[t * OUTD + tid] = acc;
    }
}

extern "C" void kernel_launch(void* const* d_in, const int* in_sizes, int n_in,
                              void* d_out, int out_size, void* d_ws, size_t ws_size,
                              hipStream_t stream)
{
    const float* x     = (const float*)d_in[0];   // [T,B,IN]
    const float* pg    = (const float*)d_in[1];   // [T,OUT]
    const float* W_ih  = (const float*)d_in[2];   // [4H,IN]
    const float* W_hh  = (const float*)d_in[3];   // [4H,H]
    const float* b_ih  = (const float*)d_in[4];
    const float* b_hh  = (const float*)d_in[5];
    const float* gamma = (const float*)d_in[6];
    const float* beta  = (const float*)d_in[7];
    const float* W_fc  = (const float*)d_in[8];   // [OUT,H+OUT]
    const float* b_fc  = (const float*)d_in[9];
    const float* dmask = (const float*)d_in[10];  // [B,H]
    float* y = (float*)d_out;

    // Workspace: h_all[chunkT,B,H] + pre_g[chunkT,B,NG] + state[2,B,H].
    const size_t state_bytes = 2ull * BB * HH * sizeof(float);
    const size_t per_t = (size_t)BB * (HH + NG) * sizeof(float);
    size_t avail = (ws_size > state_bytes) ? (ws_size - state_bytes) : 0;
    int chunkT = (int)(avail / per_t);
    if (chunkT > TT) chunkT = TT;
    if (chunkT < 1) chunkT = 1;

    float* h_all = (float*)d_ws;
    float* preg  = h_all + (size_t)chunkT * BB * HH;
    float* state = preg  + (size_t)chunkT * BB * NG;

    int first = 1;
    for (int t0 = 0; t0 < TT; t0 += chunkT) {
        int tc = TT - t0;
        if (tc > chunkT) tc = chunkT;
        pregemm<<<dim3(tc, BB / 8), 256, 0, stream>>>(x, W_ih, b_ih, b_hh,
                                                      preg, t0, tc);
        lstm_seq<<<BB, 256, 0, stream>>>(preg, W_hh, h_all, state, tc, first);
        bn_pool_fc<<<tc, 256, 0, stream>>>(h_all, gamma, beta, dmask, pg,
                                           W_fc, b_fc, y, t0, tc);
        first = 0;
    }
}